// Round 11
// baseline (264.083 us; speedup 1.0000x reference)
//
#include <hip/hip_runtime.h>
#include <hip/hip_bf16.h>

typedef float f32x4 __attribute__((ext_vector_type(4)));
typedef float f32x16 __attribute__((ext_vector_type(16)));
typedef int   i32x4  __attribute__((ext_vector_type(4)));
typedef int   i32x8  __attribute__((ext_vector_type(8)));

#define FP8_MAX_F 448.0f
#define SCL1 0x7F7F7F7Fu   /* e8m0 exponent 127 -> scale 1.0, all 4 bytes */

__device__ __forceinline__ float wave_max(float m) {
#pragma unroll
    for (int off = 32; off > 0; off >>= 1)
        m = fmaxf(m, __shfl_xor(m, off));
    return m;
}

// ---------------- stage 1: per-block abs-max partials (no atomics) ----------------
__global__ void amax2_kernel(const float* __restrict__ x, long nx,
                             const float* __restrict__ w, long nw,
                             float* __restrict__ px, float* __restrict__ pw,
                             int ga) {
    __shared__ float red[4];
    const float* src; long n; float* dst; int bid, blocks;
    if ((int)blockIdx.x < ga) { src = x; n = nx; dst = px; bid = blockIdx.x; blocks = ga; }
    else { src = w; n = nw; dst = pw; bid = blockIdx.x - ga; blocks = gridDim.x - ga; }

    const long stride = (long)blocks * blockDim.x * 16;
    long i = ((long)bid * blockDim.x + threadIdx.x) * 16;
    float m = 0.0f;
    for (; i < n; i += stride) {
        f32x4 v0 = *(const f32x4*)(src + i);
        f32x4 v1 = *(const f32x4*)(src + i + 4);
        f32x4 v2 = *(const f32x4*)(src + i + 8);
        f32x4 v3 = *(const f32x4*)(src + i + 12);
        float m0 = fmaxf(fmaxf(fabsf(v0.x), fabsf(v0.y)), fmaxf(fabsf(v0.z), fabsf(v0.w)));
        float m1 = fmaxf(fmaxf(fabsf(v1.x), fabsf(v1.y)), fmaxf(fabsf(v1.z), fabsf(v1.w)));
        float m2 = fmaxf(fmaxf(fabsf(v2.x), fabsf(v2.y)), fmaxf(fabsf(v2.z), fabsf(v2.w)));
        float m3 = fmaxf(fmaxf(fabsf(v3.x), fabsf(v3.y)), fmaxf(fabsf(v3.z), fabsf(v3.w)));
        m = fmaxf(m, fmaxf(fmaxf(m0, m1), fmaxf(m2, m3)));
    }
    m = wave_max(m);
    const int wave = threadIdx.x >> 6;
    if ((threadIdx.x & 63) == 0) red[wave] = m;
    __syncthreads();
    if (threadIdx.x == 0)
        dst[bid] = fmaxf(fmaxf(red[0], red[1]), fmaxf(red[2], red[3]));
}

// ---------------- stage 2: reduce partials -> amax bits (block 0 = x, block 1 = w) ----------------
__global__ void amax_final_kernel(const float* __restrict__ px, int npx,
                                  const float* __restrict__ pw, int npw,
                                  unsigned* __restrict__ amax) {
    __shared__ float red[4];
    const float* p; int n;
    if (blockIdx.x == 0) { p = px; n = npx; } else { p = pw; n = npw; }
    float m = 0.0f;
    for (int i = threadIdx.x; i < n; i += blockDim.x) m = fmaxf(m, p[i]);
    m = wave_max(m);
    const int wave = threadIdx.x >> 6;
    if ((threadIdx.x & 63) == 0) red[wave] = m;
    __syncthreads();
    if (threadIdx.x == 0) {
        m = fmaxf(fmaxf(red[0], red[1]), fmaxf(red[2], red[3]));
        amax[blockIdx.x] = __float_as_uint(m);
    }
}

// ---------------- fused quantize (8 floats/thread/iter -> uint2) ----------------
__global__ void quant2_kernel(const float* __restrict__ x, long nx8,
                              const float* __restrict__ w, long nw8,
                              const unsigned* __restrict__ amax_bits,
                              unsigned* __restrict__ qx, unsigned* __restrict__ qw,
                              int ga) {
    const float* src; long n8; unsigned* q; int bid, blocks; float a;
    if ((int)blockIdx.x < ga) { src = x; n8 = nx8; q = qx; bid = blockIdx.x; blocks = ga;
                                a = __uint_as_float(amax_bits[0]); }
    else { src = w; n8 = nw8; q = qw; bid = blockIdx.x - ga; blocks = gridDim.x - ga;
           a = __uint_as_float(amax_bits[1]); }
    const float scale = fminf(FP8_MAX_F / fmaxf(a, 1e-12f), FP8_MAX_F);

    const long stride = (long)blocks * blockDim.x;
    for (long i = (long)bid * blockDim.x + threadIdx.x; i < n8; i += stride) {
        f32x4 v0 = *(const f32x4*)(src + i * 8);
        f32x4 v1 = *(const f32x4*)(src + i * 8 + 4);
        float c0 = fminf(fmaxf(v0.x * scale, -FP8_MAX_F), FP8_MAX_F);
        float c1 = fminf(fmaxf(v0.y * scale, -FP8_MAX_F), FP8_MAX_F);
        float c2 = fminf(fmaxf(v0.z * scale, -FP8_MAX_F), FP8_MAX_F);
        float c3 = fminf(fmaxf(v0.w * scale, -FP8_MAX_F), FP8_MAX_F);
        float c4 = fminf(fmaxf(v1.x * scale, -FP8_MAX_F), FP8_MAX_F);
        float c5 = fminf(fmaxf(v1.y * scale, -FP8_MAX_F), FP8_MAX_F);
        float c6 = fminf(fmaxf(v1.z * scale, -FP8_MAX_F), FP8_MAX_F);
        float c7 = fminf(fmaxf(v1.w * scale, -FP8_MAX_F), FP8_MAX_F);
        int r0 = __builtin_amdgcn_cvt_pk_fp8_f32(c0, c1, 0, false);
        r0 = __builtin_amdgcn_cvt_pk_fp8_f32(c2, c3, r0, true);
        int r1 = __builtin_amdgcn_cvt_pk_fp8_f32(c4, c5, 0, false);
        r1 = __builtin_amdgcn_cvt_pk_fp8_f32(c6, c7, r1, true);
        uint2 rr; rr.x = (unsigned)r0; rr.y = (unsigned)r1;
        *(uint2*)(q + i * 2) = rr;
    }
}

// ---------------- fp8 GEMM, 256x256 tile, BK=128, mfma_scale 32x32x64, 2-slot dbuf ----------------
// LDS per slot/side: linear [c=0..7][row=0..255][16B] (same conflict-free unit layout as R4-R10).
// Lane (l31, g=l>>5), k-half kh: reads units (row, c=kh*4+2g) and (row, c=kh*4+2g+1) as the
// lo/hi 16B of the 32B MFMA operand. Same k->slot map on A and B => valid bijection
// (R7/R8-verified, absmax 1 ulp). Unit e8m0 scales (0x7F) => numerically plain fp8 GEMM.
// Per tile t (slot s=t&1): ONE vmcnt(0)+barrier (publishes S(t), drains stages issued in t-1),
// then STAGE_A(t+1 -> s^1), subphase kh0 {12 ds_read, lgkm0, 8 MFMA}, STAGE_B(t+1),
// subphase kh1. Single frag set (48 VGPR) keeps liveness ~206 < 256 -> no spill (R9/R10 lesson).
// WAR: slot s^1's reads (tile t-1) drained by t-1's lgkm(0)s before the barrier at top of t.
// RAW: vmcnt(0) at top of t+1 drains exactly S(t+1)'s 8 loads.
__global__ __launch_bounds__(512, 1) void gemm_fp8_kernel(
    const unsigned char* __restrict__ Xq,   // [M][K] fp8
    const unsigned char* __restrict__ Wq,   // [N][K] fp8
    const float* __restrict__ bias,         // [N]
    const unsigned* __restrict__ amax_bits, // [0]=x amax, [1]=w amax
    float* __restrict__ out,                // [M][N] f32 (bf16-rounded values)
    int M, int N, int K, int nbn)
{
    __shared__ unsigned char ldsA[2][32768];
    __shared__ unsigned char ldsB[2][32768];

    const int tid  = threadIdx.x;
    const int lane = tid & 63;
    const int wave = tid >> 6;
    const int wm128 = (wave >> 2) * 128;  // 2 M-halves
    const int wn64  = (wave & 3) * 64;    // 4 N-quarters

    const int l31 = lane & 31;
    const int g   = lane >> 5;            // k-subgroup within a 64-K half

    // XCD-aware swizzle (nwg % 8 == 0), bn-fastest for A-panel L2 reuse
    const int cpx = gridDim.x >> 3;
    const int wg  = ((int)blockIdx.x & 7) * cpx + ((int)blockIdx.x >> 3);
    const int bn = wg % nbn;
    const int bm = wg / nbn;
    const int rowStart = bm << 8;
    const int colStart = bn << 8;

    // LDS read offsets: unit (row, c) at byte c*4096 + row*16; kh adds 4 c's = 16384
    const int aoffL = (2 * g) * 4096 + (wm128 + l31) * 16;   // + kh*16384 + mt*512
    const int boffL = (2 * g) * 4096 + (wn64  + l31) * 16;   // + kh*16384 + nt*512

    // staging source offsets (fully linear; dest chunk c_ covers c = c_*2 + (tid>>8))
    const size_t aoffs = (size_t)(rowStart + (tid & 255)) * K + (tid >> 8) * 16;
    const size_t boffs = (size_t)(colStart + (tid & 255)) * K + (tid >> 8) * 16;
    const int tid16 = tid * 16;

    union Frag { i32x8 v; struct { i32x4 lo, hi; } h; };
    f32x16 acc[4][2] = {};

#define STAGE_A(t, sl)                                                                          \
    do {                                                                                        \
        const size_t kk_ = (size_t)(t) * 128;                                                   \
        _Pragma("unroll")                                                                       \
        for (int c_ = 0; c_ < 4; ++c_)                                                          \
            __builtin_amdgcn_global_load_lds(                                                   \
                (const __attribute__((address_space(1))) void*)(Xq + aoffs + kk_ + c_ * 32),    \
                (__attribute__((address_space(3))) void*)(&ldsA[sl][c_ * 8192 + tid16]),        \
                16, 0, 0);                                                                      \
    } while (0)

#define STAGE_B(t, sl)                                                                          \
    do {                                                                                        \
        const size_t kk_ = (size_t)(t) * 128;                                                   \
        _Pragma("unroll")                                                                       \
        for (int c_ = 0; c_ < 4; ++c_)                                                          \
            __builtin_amdgcn_global_load_lds(                                                   \
                (const __attribute__((address_space(1))) void*)(Wq + boffs + kk_ + c_ * 32),    \
                (__attribute__((address_space(3))) void*)(&ldsB[sl][c_ * 8192 + tid16]),        \
                16, 0, 0);                                                                      \
    } while (0)

#define RD_KH(kh, sl)                                                                           \
    do {                                                                                        \
        const unsigned char* rA_ = &ldsA[sl][0];                                                \
        const unsigned char* rB_ = &ldsB[sl][0];                                                \
        _Pragma("unroll")                                                                       \
        for (int mt_ = 0; mt_ < 4; ++mt_) {                                                     \
            fa[mt_].h.lo = *(const i32x4*)(rA_ + aoffL + (kh) * 16384 + mt_ * 512);             \
            fa[mt_].h.hi = *(const i32x4*)(rA_ + aoffL + (kh) * 16384 + 4096 + mt_ * 512);      \
        }                                                                                       \
        _Pragma("unroll")                                                                       \
        for (int nt_ = 0; nt_ < 2; ++nt_) {                                                     \
            fb[nt_].h.lo = *(const i32x4*)(rB_ + boffL + (kh) * 16384 + nt_ * 512);             \
            fb[nt_].h.hi = *(const i32x4*)(rB_ + boffL + (kh) * 16384 + 4096 + nt_ * 512);      \
        }                                                                                       \
    } while (0)

#define MFMA8()                                                                                 \
    do {                                                                                        \
        __builtin_amdgcn_s_setprio(1);                                                          \
        _Pragma("unroll")                                                                       \
        for (int mt_ = 0; mt_ < 4; ++mt_)                                                       \
            _Pragma("unroll")                                                                   \
            for (int nt_ = 0; nt_ < 2; ++nt_)                                                   \
                acc[mt_][nt_] = __builtin_amdgcn_mfma_scale_f32_32x32x64_f8f6f4(                \
                    fa[mt_].v, fb[nt_].v, acc[mt_][nt_], 0, 0, 0, SCL1, 0, SCL1);               \
        __builtin_amdgcn_s_setprio(0);                                                          \
    } while (0)

#define BODY(t, s)                                                                              \
    do {                                                                                        \
        asm volatile("s_waitcnt vmcnt(0)" ::: "memory");                                        \
        __builtin_amdgcn_s_barrier();                                                           \
        __builtin_amdgcn_sched_barrier(0);                                                      \
        if ((t) + 1 < nT) STAGE_A((t) + 1, (s) ^ 1);                                            \
        RD_KH(0, s);                                                                            \
        asm volatile("s_waitcnt lgkmcnt(0)" ::: "memory");                                      \
        __builtin_amdgcn_sched_barrier(0);                                                      \
        MFMA8();                                                                                \
        if ((t) + 1 < nT) STAGE_B((t) + 1, (s) ^ 1);                                            \
        RD_KH(1, s);                                                                            \
        asm volatile("s_waitcnt lgkmcnt(0)" ::: "memory");                                      \
        __builtin_amdgcn_sched_barrier(0);                                                      \
        MFMA8();                                                                                \
    } while (0)

    // prologue: stage tile 0 -> slot 0
    STAGE_A(0, 0); STAGE_B(0, 0);

    Frag fa[4], fb[2];
    const int nT = K >> 7;   // 8
#pragma unroll 1
    for (int t = 0; t < nT; t += 2) {
        BODY(t, 0);
        BODY(t + 1, 1);
    }
#undef BODY
#undef MFMA8
#undef RD_KH
#undef STAGE_A
#undef STAGE_B

    // ---- epilogue: dequant scale, bias, bf16 round, f32 store ----
    // 32x32 C/D layout: col = lane&31, row = (r&3) + 8*(r>>2) + 4*(lane>>5)
    const float ax = __uint_as_float(amax_bits[0]);
    const float aw = __uint_as_float(amax_bits[1]);
    const float sx = fminf(FP8_MAX_F / fmaxf(ax, 1e-12f), FP8_MAX_F);
    const float sw = fminf(FP8_MAX_F / fmaxf(aw, 1e-12f), FP8_MAX_F);
    const float sc = (1.0f / sx) * (1.0f / sw);

#pragma unroll
    for (int nt = 0; nt < 2; ++nt) {
        const int col = colStart + wn64 + nt * 32 + l31;
        const float bv = bias[col];
#pragma unroll
        for (int mt = 0; mt < 4; ++mt) {
#pragma unroll
            for (int r = 0; r < 16; ++r) {
                const int row = rowStart + wm128 + mt * 32 + (r & 3) + 8 * (r >> 2) + 4 * g;
                float tt = acc[mt][nt][r] * sc;   // mul...
                tt = tt + bv;                     // ...then add (match jnp op order)
                out[(size_t)row * N + col] = __bfloat162float(__float2bfloat16(tt));
            }
        }
    }
}

extern "C" void kernel_launch(void* const* d_in, const int* in_sizes, int n_in,
                              void* d_out, int out_size, void* d_ws, size_t ws_size,
                              hipStream_t stream) {
    const float* input  = (const float*)d_in[0];
    const float* weight = (const float*)d_in[1];
    const float* bias   = (const float*)d_in[2];
    float* out = (float*)d_out;

    const int K = 1024;                       // weight [N,K] = [1024,1024]
    const int N = in_sizes[2];                // 1024 (bias length)
    const long nX = in_sizes[0];              // 33554432
    const long nW = (long)N * K;              // 1048576
    const int M = (int)(nX / K);              // 32768

    const int GA = 1984;                      // input blocks (of 2048 total)
    const int GW = 64;                        // weight blocks

    unsigned char* ws = (unsigned char*)d_ws;
    unsigned* amax = (unsigned*)ws;           // [0]=x amax bits, [1]=w amax bits
    unsigned char* Xq = ws + 256;
    unsigned char* Wq = Xq + (size_t)M * K;
    float* px = (float*)(Wq + (size_t)N * K); // 1984 partials
    float* pw = px + GA;                      // 64 partials

    // stage 1: per-block partials (plain stores, no atomic contention)
    amax2_kernel<<<GA + GW, 256, 0, stream>>>(input, nX, weight, nW, px, pw, GA);
    // stage 2: 2 blocks reduce partials -> amax bits (deterministic)
    amax_final_kernel<<<2, 256, 0, stream>>>(px, GA, pw, GW, amax);

    quant2_kernel<<<2048, 256, 0, stream>>>(input, nX / 8, weight, nW / 8, amax,
                                            (unsigned*)Xq, (unsigned*)Wq, GA);

    const int nbn = N / 256;                  // 4
    const int nwg = (M / 256) * nbn;          // 512
    gemm_fp8_kernel<<<dim3(nwg), dim3(512), 0, stream>>>(Xq, Wq, bias, amax, out, M, N, K, nbn);
}

// Round 12
// 122.849 us; speedup vs baseline: 2.1497x; 2.1497x over previous
//
#include <hip/hip_runtime.h>
#include <hip/hip_bf16.h>

typedef float f32x4 __attribute__((ext_vector_type(4)));
typedef float f32x16 __attribute__((ext_vector_type(16)));
typedef int   i32x4  __attribute__((ext_vector_type(4)));
typedef int   i32x8  __attribute__((ext_vector_type(8)));

#define FP8_MAX_F 448.0f
#define SCL1 0x7F7F7F7Fu   /* e8m0 exponent 127 -> scale 1.0, all 4 bytes */

__device__ __forceinline__ float wave_max(float m) {
#pragma unroll
    for (int off = 32; off > 0; off >>= 1)
        m = fmaxf(m, __shfl_xor(m, off));
    return m;
}

// ---------------- stage 1: per-block abs-max partials (no atomics) ----------------
__global__ void amax2_kernel(const float* __restrict__ x, long nx,
                             const float* __restrict__ w, long nw,
                             float* __restrict__ px, float* __restrict__ pw,
                             int ga) {
    __shared__ float red[4];
    const float* src; long n; float* dst; int bid, blocks;
    if ((int)blockIdx.x < ga) { src = x; n = nx; dst = px; bid = blockIdx.x; blocks = ga; }
    else { src = w; n = nw; dst = pw; bid = blockIdx.x - ga; blocks = gridDim.x - ga; }

    const long stride = (long)blocks * blockDim.x * 16;
    long i = ((long)bid * blockDim.x + threadIdx.x) * 16;
    float m = 0.0f;
    for (; i < n; i += stride) {
        f32x4 v0 = *(const f32x4*)(src + i);
        f32x4 v1 = *(const f32x4*)(src + i + 4);
        f32x4 v2 = *(const f32x4*)(src + i + 8);
        f32x4 v3 = *(const f32x4*)(src + i + 12);
        float m0 = fmaxf(fmaxf(fabsf(v0.x), fabsf(v0.y)), fmaxf(fabsf(v0.z), fabsf(v0.w)));
        float m1 = fmaxf(fmaxf(fabsf(v1.x), fabsf(v1.y)), fmaxf(fabsf(v1.z), fabsf(v1.w)));
        float m2 = fmaxf(fmaxf(fabsf(v2.x), fabsf(v2.y)), fmaxf(fabsf(v2.z), fabsf(v2.w)));
        float m3 = fmaxf(fmaxf(fabsf(v3.x), fabsf(v3.y)), fmaxf(fabsf(v3.z), fabsf(v3.w)));
        m = fmaxf(m, fmaxf(fmaxf(m0, m1), fmaxf(m2, m3)));
    }
    m = wave_max(m);
    const int wave = threadIdx.x >> 6;
    if ((threadIdx.x & 63) == 0) red[wave] = m;
    __syncthreads();
    if (threadIdx.x == 0)
        dst[bid] = fmaxf(fmaxf(red[0], red[1]), fmaxf(red[2], red[3]));
}

// ---------------- fused quantize (inline amax finalization; 8 floats/thread/iter) ----------------
// Scale is recomputed per block from the partials (fmax is exact -> any reduction order
// gives the bitwise-identical max -> deterministic and identical to the GEMM's epilogue value).
__global__ void quant2_kernel(const float* __restrict__ x, long nx8,
                              const float* __restrict__ w, long nw8,
                              const float* __restrict__ px, const float* __restrict__ pw,
                              int npx,
                              unsigned* __restrict__ qx, unsigned* __restrict__ qw,
                              int ga) {
    __shared__ float red[4];
    const float* src; long n8; unsigned* q; int bid, blocks; float a;
    if ((int)blockIdx.x < ga) {
        src = x; n8 = nx8; q = qx; bid = blockIdx.x; blocks = ga;
        float mx = 0.0f;
        for (int i = threadIdx.x; i < npx; i += 256) mx = fmaxf(mx, px[i]);
        mx = wave_max(mx);
        if ((threadIdx.x & 63) == 0) red[threadIdx.x >> 6] = mx;
        __syncthreads();
        a = fmaxf(fmaxf(red[0], red[1]), fmaxf(red[2], red[3]));
    } else {
        src = w; n8 = nw8; q = qw; bid = blockIdx.x - ga; blocks = gridDim.x - ga;
        a = wave_max(pw[threadIdx.x & 63]);   // 64 partials: one wave covers all
    }
    const float scale = fminf(FP8_MAX_F / fmaxf(a, 1e-12f), FP8_MAX_F);

    const long stride = (long)blocks * blockDim.x;
    for (long i = (long)bid * blockDim.x + threadIdx.x; i < n8; i += stride) {
        f32x4 v0 = *(const f32x4*)(src + i * 8);
        f32x4 v1 = *(const f32x4*)(src + i * 8 + 4);
        float c0 = fminf(fmaxf(v0.x * scale, -FP8_MAX_F), FP8_MAX_F);
        float c1 = fminf(fmaxf(v0.y * scale, -FP8_MAX_F), FP8_MAX_F);
        float c2 = fminf(fmaxf(v0.z * scale, -FP8_MAX_F), FP8_MAX_F);
        float c3 = fminf(fmaxf(v0.w * scale, -FP8_MAX_F), FP8_MAX_F);
        float c4 = fminf(fmaxf(v1.x * scale, -FP8_MAX_F), FP8_MAX_F);
        float c5 = fminf(fmaxf(v1.y * scale, -FP8_MAX_F), FP8_MAX_F);
        float c6 = fminf(fmaxf(v1.z * scale, -FP8_MAX_F), FP8_MAX_F);
        float c7 = fminf(fmaxf(v1.w * scale, -FP8_MAX_F), FP8_MAX_F);
        int r0 = __builtin_amdgcn_cvt_pk_fp8_f32(c0, c1, 0, false);
        r0 = __builtin_amdgcn_cvt_pk_fp8_f32(c2, c3, r0, true);
        int r1 = __builtin_amdgcn_cvt_pk_fp8_f32(c4, c5, 0, false);
        r1 = __builtin_amdgcn_cvt_pk_fp8_f32(c6, c7, r1, true);
        uint2 rr; rr.x = (unsigned)r0; rr.y = (unsigned)r1;
        *(uint2*)(q + i * 2) = rr;
    }
}

// ---------------- fp8 GEMM, 256x256 tile, BK=64, mfma_scale 32x32x64, read-ahead pipeline ----------------
// R8 structure verbatim (best measured: ~65 us GEMM, 119.5 us total; absmax 1 ulp).
// LDS per slot/side: linear [c=0..3][row=0..255][16B] (conflict-free, verified: 0 conflicts).
// Lane (l31, g=l>>5) reads units (row, c=2g) and (row, c=2g+1); unit e8m0 scales (0x7F) make
// mfma_scale numerically == plain fp8 GEMM at the 2x MX rate.
//   BODY(t): STAGE(t+2) ; lgkm0 (frags(t) ready) ; MFMA8 ; vmcnt(4) counted ; barrier ;
//            RD_FRAGS(t+1)   [slot published by that barrier]
// WAR: a slot's reads drain (lgkm0) one barrier before its restage. RAW: vmcnt(4) leaves
// exactly S(t+2) in flight -> S(t+1) retired, published by the barrier.
__global__ __launch_bounds__(512, 1) void gemm_fp8_kernel(
    const unsigned char* __restrict__ Xq,   // [M][K] fp8
    const unsigned char* __restrict__ Wq,   // [N][K] fp8
    const float* __restrict__ bias,         // [N]
    const float* __restrict__ px,           // [npx] input amax partials
    const float* __restrict__ pw,           // [64]  weight amax partials
    int npx,
    float* __restrict__ out,                // [M][N] f32 (bf16-rounded values)
    int M, int N, int K, int nbn)
{
    __shared__ unsigned char ldsA[3][16384];
    __shared__ unsigned char ldsB[3][16384];
    __shared__ float redX[8];

    const int tid  = threadIdx.x;
    const int lane = tid & 63;
    const int wave = tid >> 6;
    const int wm128 = (wave >> 2) * 128;  // 2 M-halves
    const int wn64  = (wave & 3) * 64;    // 4 N-quarters

    const int l31 = lane & 31;
    const int g   = lane >> 5;            // k-group: 0 -> k 0..31, 1 -> k 32..63

    // XCD-aware swizzle (nwg % 8 == 0), bn-fastest for A-panel L2 reuse
    const int cpx = gridDim.x >> 3;
    const int wg  = ((int)blockIdx.x & 7) * cpx + ((int)blockIdx.x >> 3);
    const int bn = wg % nbn;
    const int bm = wg / nbn;
    const int rowStart = bm << 8;
    const int colStart = bn << 8;

    // LDS read offsets: low 16B at c=2g, high 16B at c=2g+1 (+4096)
    const int aoffL = (2 * g) * 4096 + (wm128 + l31) * 16;   // + mt*512
    const int boffL = (2 * g) * 4096 + (wn64  + l31) * 16;   // + nt*512

    // staging source offsets (fully linear; dest = tid*16)
    const size_t aoffs = (size_t)(rowStart + (tid & 255)) * K + (tid >> 8) * 16;
    const size_t boffs = (size_t)(colStart + (tid & 255)) * K + (tid >> 8) * 16;
    const int tid16 = tid * 16;

    union Frag { i32x8 v; struct { i32x4 lo, hi; } h; };
    f32x16 acc[4][2] = {};

#define STAGE_A(t, sl)                                                                          \
    do {                                                                                        \
        const size_t kk_ = (size_t)(t) * 64;                                                    \
        __builtin_amdgcn_global_load_lds(                                                       \
            (const __attribute__((address_space(1))) void*)(Xq + aoffs + kk_),                  \
            (__attribute__((address_space(3))) void*)(&ldsA[sl][tid16]), 16, 0, 0);             \
        __builtin_amdgcn_global_load_lds(                                                       \
            (const __attribute__((address_space(1))) void*)(Xq + aoffs + 32 + kk_),             \
            (__attribute__((address_space(3))) void*)(&ldsA[sl][8192 + tid16]), 16, 0, 0);      \
    } while (0)

#define STAGE_B(t, sl)                                                                          \
    do {                                                                                        \
        const size_t kk_ = (size_t)(t) * 64;                                                    \
        __builtin_amdgcn_global_load_lds(                                                       \
            (const __attribute__((address_space(1))) void*)(Wq + boffs + kk_),                  \
            (__attribute__((address_space(3))) void*)(&ldsB[sl][tid16]), 16, 0, 0);             \
        __builtin_amdgcn_global_load_lds(                                                       \
            (const __attribute__((address_space(1))) void*)(Wq + boffs + 32 + kk_),             \
            (__attribute__((address_space(3))) void*)(&ldsB[sl][8192 + tid16]), 16, 0, 0);      \
    } while (0)

#define RD_FRAGS(sl, FA, FB)                                                                    \
    do {                                                                                        \
        const unsigned char* rA_ = &ldsA[sl][0];                                                \
        const unsigned char* rB_ = &ldsB[sl][0];                                                \
        _Pragma("unroll")                                                                       \
        for (int mt_ = 0; mt_ < 4; ++mt_) {                                                     \
            FA[mt_].h.lo = *(const i32x4*)(rA_ + aoffL + mt_ * 512);                            \
            FA[mt_].h.hi = *(const i32x4*)(rA_ + aoffL + 4096 + mt_ * 512);                     \
        }                                                                                       \
        _Pragma("unroll")                                                                       \
        for (int nt_ = 0; nt_ < 2; ++nt_) {                                                     \
            FB[nt_].h.lo = *(const i32x4*)(rB_ + boffL + nt_ * 512);                            \
            FB[nt_].h.hi = *(const i32x4*)(rB_ + boffL + 4096 + nt_ * 512);                     \
        }                                                                                       \
    } while (0)

#define MFMA8(FA, FB)                                                                           \
    do {                                                                                        \
        __builtin_amdgcn_s_setprio(1);                                                          \
        _Pragma("unroll")                                                                       \
        for (int mt_ = 0; mt_ < 4; ++mt_)                                                       \
            _Pragma("unroll")                                                                   \
            for (int nt_ = 0; nt_ < 2; ++nt_)                                                   \
                acc[mt_][nt_] = __builtin_amdgcn_mfma_scale_f32_32x32x64_f8f6f4(                \
                    FA[mt_].v, FB[nt_].v, acc[mt_][nt_], 0, 0, 0, SCL1, 0, SCL1);               \
        __builtin_amdgcn_s_setprio(0);                                                          \
    } while (0)

// One K-tile: stage(t+2) -> lgkm0 (this tile's frags ready) -> 8 MFMA ->
// counted vmcnt(4) (S(t+1) landed, S(t+2) in flight) -> barrier -> read frags of t+1.
#define BODY(t, sNext, sStage, FA, FB, FA2, FB2)                                                \
    do {                                                                                        \
        if ((t) + 2 < nT) { STAGE_A((t) + 2, sStage); STAGE_B((t) + 2, sStage); }               \
        asm volatile("s_waitcnt lgkmcnt(0)" ::: "memory");                                      \
        __builtin_amdgcn_sched_barrier(0);                                                      \
        MFMA8(FA, FB);                                                                          \
        if ((t) + 2 < nT) asm volatile("s_waitcnt vmcnt(4)" ::: "memory");                      \
        else              asm volatile("s_waitcnt vmcnt(0)" ::: "memory");                      \
        __builtin_amdgcn_s_barrier();                                                           \
        __builtin_amdgcn_sched_barrier(0);                                                      \
        if ((t) + 1 < nT) RD_FRAGS(sNext, FA2, FB2);                                            \
    } while (0)

    // prologue: stage tiles 0,1 -> slots 0,1; publish tile 0 (S(1) stays in flight)
    STAGE_A(0, 0); STAGE_B(0, 0);
    STAGE_A(1, 1); STAGE_B(1, 1);
    asm volatile("s_waitcnt vmcnt(4)" ::: "memory");
    __builtin_amdgcn_s_barrier();
    __builtin_amdgcn_sched_barrier(0);

    Frag faA[4], fbA[2], faB[4], fbB[2];
    RD_FRAGS(0, faA, fbA);

    const int nT = K >> 6;   // 16
    int s = 0;
#pragma unroll 1
    for (int t = 0; t < nT; t += 2) {
        const int s1 = (s + 1 >= 3) ? s - 2 : s + 1;
        const int s2 = (s + 2 >= 3) ? s - 1 : s + 2;
        BODY(t,     s1, s2, faA, fbA, faB, fbB);   // tile t in slot s
        BODY(t + 1, s2, s,  faB, fbB, faA, fbA);   // tile t+1 in slot s1; stage t+3 -> s
        s = s2;
    }
#undef BODY
#undef MFMA8
#undef RD_FRAGS
#undef STAGE_A
#undef STAGE_B

    // ---- inline amax finalization (replaces the amax_final dispatch) ----
    // fmax is exact: any reduction order yields the bitwise-identical max, so this matches
    // quant2's per-block value exactly.
    float mx = 0.0f;
    for (int i = tid; i < npx; i += 512) mx = fmaxf(mx, px[i]);
    mx = wave_max(mx);
    const float aw = wave_max(pw[lane]);      // 64 partials: one wave covers all
    if (lane == 0) redX[wave] = mx;
    __syncthreads();
    float ax = redX[0];
#pragma unroll
    for (int i2 = 1; i2 < 8; ++i2) ax = fmaxf(ax, redX[i2]);

    // ---- epilogue: dequant scale, bias, bf16 round, f32 store ----
    // 32x32 C/D layout: col = lane&31, row = (r&3) + 8*(r>>2) + 4*(lane>>5)
    const float sx = fminf(FP8_MAX_F / fmaxf(ax, 1e-12f), FP8_MAX_F);
    const float sw = fminf(FP8_MAX_F / fmaxf(aw, 1e-12f), FP8_MAX_F);
    const float sc = (1.0f / sx) * (1.0f / sw);

#pragma unroll
    for (int nt = 0; nt < 2; ++nt) {
        const int col = colStart + wn64 + nt * 32 + l31;
        const float bv = bias[col];
#pragma unroll
        for (int mt = 0; mt < 4; ++mt) {
#pragma unroll
            for (int r = 0; r < 16; ++r) {
                const int row = rowStart + wm128 + mt * 32 + (r & 3) + 8 * (r >> 2) + 4 * g;
                float tt = acc[mt][nt][r] * sc;   // mul...
                tt = tt + bv;                     // ...then add (match jnp op order)
                out[(size_t)row * N + col] = __bfloat162float(__float2bfloat16(tt));
            }
        }
    }
}

extern "C" void kernel_launch(void* const* d_in, const int* in_sizes, int n_in,
                              void* d_out, int out_size, void* d_ws, size_t ws_size,
                              hipStream_t stream) {
    const float* input  = (const float*)d_in[0];
    const float* weight = (const float*)d_in[1];
    const float* bias   = (const float*)d_in[2];
    float* out = (float*)d_out;

    const int K = 1024;                       // weight [N,K] = [1024,1024]
    const int N = in_sizes[2];                // 1024 (bias length)
    const long nX = in_sizes[0];              // 33554432
    const long nW = (long)N * K;              // 1048576
    const int M = (int)(nX / K);              // 32768

    const int GA = 1984;                      // input blocks (of 2048 total)
    const int GW = 64;                        // weight blocks

    unsigned char* ws = (unsigned char*)d_ws;
    unsigned char* Xq = ws + 256;
    unsigned char* Wq = Xq + (size_t)M * K;
    float* px = (float*)(Wq + (size_t)N * K); // 1984 partials
    float* pw = px + GA;                      // 64 partials

    // stage 1: per-block partials (plain stores, no atomic contention)
    amax2_kernel<<<GA + GW, 256, 0, stream>>>(input, nX, weight, nW, px, pw, GA);

    // quantize (finalizes amax inline from partials)
    quant2_kernel<<<2048, 256, 0, stream>>>(input, nX / 8, weight, nW / 8, px, pw, GA,
                                            (unsigned*)Xq, (unsigned*)Wq, GA);

    const int nbn = N / 256;                  // 4
    const int nwg = (M / 256) * nbn;          // 512
    gemm_fp8_kernel<<<dim3(nwg), dim3(512), 0, stream>>>(Xq, Wq, bias, px, pw, GA,
                                                         out, M, N, K, nbn);
}